// Round 1
// baseline (1114.133 us; speedup 1.0000x reference)
//
#include <hip/hip_runtime.h>
#include <cmath>

constexpr int NPTS = 262144;
constexpr int LVLS = 16;
constexpr int TSZ  = 524288;
constexpr unsigned TMASK = TSZ - 1u;
constexpr unsigned P1 = 2654435761u;
constexpr unsigned P2 = 805459861u;

struct LevelParams {
  float scale[LVLS];
  int   res[LVLS];
  int   dense[LVLS];
};

__global__ __launch_bounds__(256)
void ngp_fused(const float* __restrict__ xyzs,
               const float* __restrict__ dirs,
               const float* __restrict__ ta1,
               const float* __restrict__ ta2,
               const float* __restrict__ tb1,
               const float* __restrict__ tb2,
               const float* __restrict__ tst,
               const float* __restrict__ w1,
               const float* __restrict__ w2,
               const float* __restrict__ wc1,
               const float* __restrict__ wc2,
               const float* __restrict__ wc3,
               float* __restrict__ out,
               LevelParams lp)
{
  const int n = blockIdx.x * 256 + threadIdx.x;
  if (n >= NPTS) return;

  // ---- time blend weights (uniform across all threads; t == xyzs[0][3]) ----
  const float t = xyzs[3];
  float ft = t * 16.0f;
  float fr = ft - floorf(ft);
  float prev1 = 1.0f - fr;
  float next1 = 1.0f - prev1;
  const float ss1 = prev1 + next1;
  prev1 = prev1 / ss1; next1 = next1 / ss1;
  ft = t * 20.0f;
  fr = ft - floorf(ft);
  float prev2 = 1.0f - fr;
  float next2 = 1.0f - prev2;
  const float ss2 = prev2 + next2;
  prev2 = prev2 / ss2; next2 = next2 / ss2;

  // ---- point coords mapped to [0,1] ----
  const float4 xin = reinterpret_cast<const float4*>(xyzs)[n];
  const float px = (xin.x + 1.0f) * 0.5f;
  const float py = (xin.y + 1.0f) * 0.5f;
  const float pz = (xin.z + 1.0f) * 0.5f;

  // layer-1 accumulators: hidden = hash_res @ w1, built level by level
  float h1[64];
  #pragma unroll
  for (int j = 0; j < 64; ++j) h1[j] = 0.0f;

  const size_t f1base = (size_t)4 * NPTS + (size_t)n * 16;
  const size_t f2base = (size_t)20 * NPTS + (size_t)n * 16;

  const float2* tba1 = reinterpret_cast<const float2*>(ta1);
  const float2* tba2 = reinterpret_cast<const float2*>(ta2);
  const float2* tbb1 = reinterpret_cast<const float2*>(tb1);
  const float2* tbb2 = reinterpret_cast<const float2*>(tb2);
  const float2* tbst = reinterpret_cast<const float2*>(tst);

  for (int l = 0; l < LVLS; ++l) {
    const float s = lp.scale[l];
    const int res = lp.res[l];

    const float fx = px * s + 0.5f; const float f0x = floorf(fx); const float wx = fx - f0x;
    const float fy = py * s + 0.5f; const float f0y = floorf(fy); const float wy = fy - f0y;
    const float fz = pz * s + 0.5f; const float f0z = floorf(fz); const float wz = fz - f0z;
    const int ix = (int)f0x, iy = (int)f0y, iz = (int)f0z;

    unsigned idx[8];
    if (lp.dense[l]) {            // uniform branch (same for all threads)
      const int r2 = res * res;
      const int bx0 = ix,        bx1 = ix + 1;
      const int by0 = iy * res,  by1 = by0 + res;
      const int bz0 = iz * r2,   bz1 = bz0 + r2;
      idx[0] = (unsigned)(bx0 + by0 + bz0);
      idx[1] = (unsigned)(bx1 + by0 + bz0);
      idx[2] = (unsigned)(bx0 + by1 + bz0);
      idx[3] = (unsigned)(bx1 + by1 + bz0);
      idx[4] = (unsigned)(bx0 + by0 + bz1);
      idx[5] = (unsigned)(bx1 + by0 + bz1);
      idx[6] = (unsigned)(bx0 + by1 + bz1);
      idx[7] = (unsigned)(bx1 + by1 + bz1);
    } else {
      const unsigned hx0 = (unsigned)ix,      hx1 = hx0 + 1u;
      const unsigned hy0 = (unsigned)iy * P1, hy1 = hy0 + P1;
      const unsigned hz0 = (unsigned)iz * P2, hz1 = hz0 + P2;
      idx[0] = (hx0 ^ hy0 ^ hz0) & TMASK;
      idx[1] = (hx1 ^ hy0 ^ hz0) & TMASK;
      idx[2] = (hx0 ^ hy1 ^ hz0) & TMASK;
      idx[3] = (hx1 ^ hy1 ^ hz0) & TMASK;
      idx[4] = (hx0 ^ hy0 ^ hz1) & TMASK;
      idx[5] = (hx1 ^ hy0 ^ hz1) & TMASK;
      idx[6] = (hx0 ^ hy1 ^ hz1) & TMASK;
      idx[7] = (hx1 ^ hy1 ^ hz1) & TMASK;
    }

    const float wxa = 1.0f - wx, wya = 1.0f - wy, wza = 1.0f - wz;
    float wv[8];
    wv[0] = wxa * wya * wza;
    wv[1] = wx  * wya * wza;
    wv[2] = wxa * wy  * wza;
    wv[3] = wx  * wy  * wza;
    wv[4] = wxa * wya * wz;
    wv[5] = wx  * wya * wz;
    wv[6] = wxa * wy  * wz;
    wv[7] = wx  * wy  * wz;

    const size_t lbase = (size_t)l * TSZ;
    const float2* ba1 = tba1 + lbase;
    const float2* ba2 = tba2 + lbase;
    const float2* bb1 = tbb1 + lbase;
    const float2* bb2 = tbb2 + lbase;
    const float2* bst = tbst + lbase;

    // issue all 40 gathers, then reduce (compiler schedules loads together)
    float2 va1[8], va2[8], vb1[8], vb2[8], vst[8];
    #pragma unroll
    for (int c = 0; c < 8; ++c) {
      const unsigned id = idx[c];
      va1[c] = ba1[id];
      va2[c] = ba2[id];
      vb1[c] = bb1[id];
      vb2[c] = bb2[id];
      vst[c] = bst[id];
    }

    float a10 = 0.f, a11 = 0.f, a20 = 0.f, a21 = 0.f;
    float b10 = 0.f, b11 = 0.f, b20 = 0.f, b21 = 0.f;
    float st0 = 0.f, st1 = 0.f;
    #pragma unroll
    for (int c = 0; c < 8; ++c) {
      const float w = wv[c];
      a10 += va1[c].x * w; a11 += va1[c].y * w;
      a20 += va2[c].x * w; a21 += va2[c].y * w;
      b10 += vb1[c].x * w; b11 += vb1[c].y * w;
      b20 += vb2[c].x * w; b21 += vb2[c].y * w;
      st0 += vst[c].x * w; st1 += vst[c].y * w;
    }

    const float ba0f = a10 * prev1 + a20 * next1;
    const float ba1f = a11 * prev1 + a21 * next1;
    const float bb0f = b10 * prev2 + b20 * next2;
    const float bb1f = b11 * prev2 + b21 * next2;

    // hash_res rows: blend_a -> 2l,2l+1 ; blend_b -> 32+2l,33+2l ; static -> 64+2l,65+2l
    const float* wr0 = w1 + (size_t)(2 * l) * 64;
    const float* wr1 = w1 + (size_t)(2 * l + 1) * 64;
    const float* wr2 = w1 + (size_t)(32 + 2 * l) * 64;
    const float* wr3 = w1 + (size_t)(33 + 2 * l) * 64;
    const float* wr4 = w1 + (size_t)(64 + 2 * l) * 64;
    const float* wr5 = w1 + (size_t)(65 + 2 * l) * 64;
    #pragma unroll
    for (int j = 0; j < 64; ++j) {
      float acc = h1[j];
      acc += ba0f * wr0[j];
      acc += ba1f * wr1[j];
      acc += bb0f * wr2[j];
      acc += bb1f * wr3[j];
      acc += st0  * wr4[j];
      acc += st1  * wr5[j];
      h1[j] = acc;
    }

    // feature1 = [fa1[:,24:32] | fb1[:,24:32]]; feature2 = [fa2 | fb2] same cols
    if (l >= 12) {
      const size_t fo = (size_t)(l - 12) * 2;
      float2* o;
      o = reinterpret_cast<float2*>(out + f1base + fo);     *o = make_float2(a10, a11);
      o = reinterpret_cast<float2*>(out + f1base + 8 + fo); *o = make_float2(b10, b11);
      o = reinterpret_cast<float2*>(out + f2base + fo);     *o = make_float2(a20, a21);
      o = reinterpret_cast<float2*>(out + f2base + 8 + fo); *o = make_float2(b20, b21);
    }
  }

  // ---- layer 2: h2 = relu(h1) @ w2  ([64,16]) ----
  float h2[16];
  #pragma unroll
  for (int j = 0; j < 16; ++j) h2[j] = 0.0f;
  #pragma unroll
  for (int k = 0; k < 64; ++k) {
    const float a = fmaxf(h1[k], 0.0f);
    #pragma unroll
    for (int j = 0; j < 16; ++j) h2[j] += a * w2[k * 16 + j];
  }

  // sigma = exp(h2[0])
  out[(size_t)3 * NPTS + n] = expf(h2[0]);

  // ---- SH degree 4 ----
  const float dx = dirs[(size_t)n * 3 + 0] * 2.0f - 1.0f;
  const float dy = dirs[(size_t)n * 3 + 1] * 2.0f - 1.0f;
  const float dz = dirs[(size_t)n * 3 + 2] * 2.0f - 1.0f;
  const float xy = dx * dy, xz = dx * dz, yz = dy * dz;
  const float x2 = dx * dx, y2 = dy * dy, z2 = dz * dz;
  float sh[16];
  sh[0]  = 0.28209479177387814f;
  sh[1]  = -0.48860251190291987f * dy;
  sh[2]  = 0.48860251190291987f * dz;
  sh[3]  = -0.48860251190291987f * dx;
  sh[4]  = 1.0925484305920792f * xy;
  sh[5]  = -1.0925484305920792f * yz;
  sh[6]  = 0.94617469575756f * z2 - 0.31539156525252005f;
  sh[7]  = -1.0925484305920792f * xz;
  sh[8]  = 0.5462742152960396f * (x2 - y2);
  sh[9]  = 0.5900435899266435f * dy * (-3.0f * x2 + y2);
  sh[10] = 2.890611442640554f * xy * dz;
  sh[11] = 0.4570457994644657f * dy * (1.0f - 5.0f * z2);
  sh[12] = 0.3731763325901154f * dz * (5.0f * z2 - 3.0f);
  sh[13] = 0.4570457994644657f * dx * (1.0f - 5.0f * z2);
  sh[14] = 1.445305721320277f * dz * (x2 - y2);
  sh[15] = 0.5900435899266435f * dx * (-x2 + 3.0f * y2);

  // ---- c1: r1 = relu(ch @ wc1), ch = [sh(16) | h2(16)] ----
  float r1[64];
  #pragma unroll
  for (int j = 0; j < 64; ++j) r1[j] = 0.0f;
  #pragma unroll
  for (int k = 0; k < 16; ++k) {
    const float a = sh[k];
    #pragma unroll
    for (int j = 0; j < 64; ++j) r1[j] += a * wc1[(size_t)k * 64 + j];
  }
  #pragma unroll
  for (int k = 0; k < 16; ++k) {
    const float a = h2[k];
    #pragma unroll
    for (int j = 0; j < 64; ++j) r1[j] += a * wc1[(size_t)(16 + k) * 64 + j];
  }
  #pragma unroll
  for (int j = 0; j < 64; ++j) r1[j] = fmaxf(r1[j], 0.0f);

  // ---- c2: r2 = relu(r1 @ wc2)  ([64,64]) ----
  float r2[64];
  #pragma unroll
  for (int j = 0; j < 64; ++j) r2[j] = 0.0f;
  #pragma unroll
  for (int k = 0; k < 64; ++k) {
    const float a = r1[k];
    #pragma unroll
    for (int j = 0; j < 64; ++j) r2[j] += a * wc2[(size_t)k * 64 + j];
  }

  // ---- c3 + sigmoid ----
  float c0a = 0.f, c1a = 0.f, c2a = 0.f;
  #pragma unroll
  for (int k = 0; k < 64; ++k) {
    const float a = fmaxf(r2[k], 0.0f);
    c0a += a * wc3[k * 3 + 0];
    c1a += a * wc3[k * 3 + 1];
    c2a += a * wc3[k * 3 + 2];
  }
  out[(size_t)n * 3 + 0] = 1.0f / (1.0f + expf(-c0a));
  out[(size_t)n * 3 + 1] = 1.0f / (1.0f + expf(-c1a));
  out[(size_t)n * 3 + 2] = 1.0f / (1.0f + expf(-c2a));
}

extern "C" void kernel_launch(void* const* d_in, const int* in_sizes, int n_in,
                              void* d_out, int out_size, void* d_ws, size_t ws_size,
                              hipStream_t stream) {
  const float* xyzs = (const float*)d_in[0];
  const float* dirs = (const float*)d_in[1];
  const float* ta1  = (const float*)d_in[2];
  const float* ta2  = (const float*)d_in[3];
  const float* tb1  = (const float*)d_in[4];
  const float* tb2  = (const float*)d_in[5];
  const float* tst  = (const float*)d_in[6];
  const float* w1   = (const float*)d_in[7];
  const float* w2   = (const float*)d_in[8];
  const float* wc1  = (const float*)d_in[9];
  const float* wc2  = (const float*)d_in[10];
  const float* wc3  = (const float*)d_in[11];

  LevelParams lp;
  const double B = exp(log(4096.0 / 16.0) / 15.0);
  for (int l = 0; l < LVLS; ++l) {
    const double s = 16.0 * pow(B, (double)l) - 1.0;
    lp.scale[l] = (float)s;
    const int res = (int)ceil(s) + 1;
    lp.res[l] = res;
    lp.dense[l] = ((long long)res * res * res <= (long long)TSZ) ? 1 : 0;
  }

  ngp_fused<<<NPTS / 256, 256, 0, stream>>>(
      xyzs, dirs, ta1, ta2, tb1, tb2, tst,
      w1, w2, wc1, wc2, wc3, (float*)d_out, lp);
}

// Round 2
// 664.730 us; speedup vs baseline: 1.6761x; 1.6761x over previous
//
#include <hip/hip_runtime.h>
#include <cmath>

constexpr int NPTS = 262144;
constexpr int LVLS = 16;
constexpr int TSZ  = 524288;
constexpr unsigned TMASK = TSZ - 1u;
constexpr unsigned P1 = 2654435761u;
constexpr unsigned P2 = 805459861u;
// packed entry: 3 x uint2 = 24B = [a1.xy, a2.xy][b1.xy, b2.xy][st.xy, pad] as bf16 pairs
constexpr size_t PACKED_BYTES = (size_t)LVLS * TSZ * 24;

struct LevelParams {
  float scale[LVLS];
  int   res[LVLS];
  int   dense[LVLS];
};

__device__ __forceinline__ unsigned bfbits(float f) {
  // round-to-nearest-even f32 -> bf16 bits (data is finite, no NaN handling needed)
  unsigned u = __float_as_uint(f);
  return (u + 0x7fffu + ((u >> 16) & 1u)) >> 16;
}
__device__ __forceinline__ unsigned packbf(float lo, float hi) {
  return bfbits(lo) | (bfbits(hi) << 16);
}
__device__ __forceinline__ float bflo(unsigned w) { return __uint_as_float(w << 16); }
__device__ __forceinline__ float bfhi(unsigned w) { return __uint_as_float(w & 0xffff0000u); }

__global__ __launch_bounds__(256)
void repack_tables(const float2* __restrict__ ta1, const float2* __restrict__ ta2,
                   const float2* __restrict__ tb1, const float2* __restrict__ tb2,
                   const float2* __restrict__ tst, uint2* __restrict__ packed)
{
  const size_t i = (size_t)blockIdx.x * 256 + threadIdx.x;   // i = l*TSZ + idx
  const float2 a1 = ta1[i], a2 = ta2[i], b1 = tb1[i], b2 = tb2[i], st = tst[i];
  uint2 e0, e1, e2;
  e0.x = packbf(a1.x, a1.y); e0.y = packbf(a2.x, a2.y);
  e1.x = packbf(b1.x, b1.y); e1.y = packbf(b2.x, b2.y);
  e2.x = packbf(st.x, st.y); e2.y = 0u;
  uint2* o = packed + i * 3;
  o[0] = e0; o[1] = e1; o[2] = e2;
}

template<bool PACKED>
__global__ __launch_bounds__(256)
void ngp_fused(const float* __restrict__ xyzs,
               const float* __restrict__ dirs,
               const float* __restrict__ ta1,
               const float* __restrict__ ta2,
               const float* __restrict__ tb1,
               const float* __restrict__ tb2,
               const float* __restrict__ tst,
               const uint2* __restrict__ pk,
               const float* __restrict__ w1,
               const float* __restrict__ w2,
               const float* __restrict__ wc1,
               const float* __restrict__ wc2,
               const float* __restrict__ wc3,
               float* __restrict__ out,
               LevelParams lp)
{
  const int n = blockIdx.x * 256 + threadIdx.x;
  if (n >= NPTS) return;

  // ---- time blend weights (uniform; t == xyzs[0][3]) ----
  const float t = xyzs[3];
  float ft = t * 16.0f;
  float fr = ft - floorf(ft);
  float prev1 = 1.0f - fr;
  float next1 = 1.0f - prev1;
  const float ss1 = prev1 + next1;
  prev1 = prev1 / ss1; next1 = next1 / ss1;
  ft = t * 20.0f;
  fr = ft - floorf(ft);
  float prev2 = 1.0f - fr;
  float next2 = 1.0f - prev2;
  const float ss2 = prev2 + next2;
  prev2 = prev2 / ss2; next2 = next2 / ss2;

  const float4 xin = reinterpret_cast<const float4*>(xyzs)[n];
  const float px = (xin.x + 1.0f) * 0.5f;
  const float py = (xin.y + 1.0f) * 0.5f;
  const float pz = (xin.z + 1.0f) * 0.5f;

  float h1[64];
  #pragma unroll
  for (int j = 0; j < 64; ++j) h1[j] = 0.0f;

  const size_t f1base = (size_t)4 * NPTS + (size_t)n * 16;
  const size_t f2base = (size_t)20 * NPTS + (size_t)n * 16;

  const float2* tba1 = reinterpret_cast<const float2*>(ta1);
  const float2* tba2 = reinterpret_cast<const float2*>(ta2);
  const float2* tbb1 = reinterpret_cast<const float2*>(tb1);
  const float2* tbb2 = reinterpret_cast<const float2*>(tb2);
  const float2* tbst = reinterpret_cast<const float2*>(tst);

  for (int l = 0; l < LVLS; ++l) {
    const float s = lp.scale[l];
    const int res = lp.res[l];

    const float fx = px * s + 0.5f; const float f0x = floorf(fx); const float wx = fx - f0x;
    const float fy = py * s + 0.5f; const float f0y = floorf(fy); const float wy = fy - f0y;
    const float fz = pz * s + 0.5f; const float f0z = floorf(fz); const float wz = fz - f0z;
    const int ix = (int)f0x, iy = (int)f0y, iz = (int)f0z;

    unsigned idx[8];
    if (lp.dense[l]) {                   // uniform branch
      const int r2 = res * res;
      const int bx0 = ix,        bx1 = ix + 1;
      const int by0 = iy * res,  by1 = by0 + res;
      const int bz0 = iz * r2,   bz1 = bz0 + r2;
      idx[0] = (unsigned)(bx0 + by0 + bz0);
      idx[1] = (unsigned)(bx1 + by0 + bz0);
      idx[2] = (unsigned)(bx0 + by1 + bz0);
      idx[3] = (unsigned)(bx1 + by1 + bz0);
      idx[4] = (unsigned)(bx0 + by0 + bz1);
      idx[5] = (unsigned)(bx1 + by0 + bz1);
      idx[6] = (unsigned)(bx0 + by1 + bz1);
      idx[7] = (unsigned)(bx1 + by1 + bz1);
    } else {
      const unsigned hx0 = (unsigned)ix,      hx1 = hx0 + 1u;
      const unsigned hy0 = (unsigned)iy * P1, hy1 = hy0 + P1;
      const unsigned hz0 = (unsigned)iz * P2, hz1 = hz0 + P2;
      idx[0] = (hx0 ^ hy0 ^ hz0) & TMASK;
      idx[1] = (hx1 ^ hy0 ^ hz0) & TMASK;
      idx[2] = (hx0 ^ hy1 ^ hz0) & TMASK;
      idx[3] = (hx1 ^ hy1 ^ hz0) & TMASK;
      idx[4] = (hx0 ^ hy0 ^ hz1) & TMASK;
      idx[5] = (hx1 ^ hy0 ^ hz1) & TMASK;
      idx[6] = (hx0 ^ hy1 ^ hz1) & TMASK;
      idx[7] = (hx1 ^ hy1 ^ hz1) & TMASK;
    }

    const float wxa = 1.0f - wx, wya = 1.0f - wy, wza = 1.0f - wz;
    float wv[8];
    wv[0] = wxa * wya * wza;
    wv[1] = wx  * wya * wza;
    wv[2] = wxa * wy  * wza;
    wv[3] = wx  * wy  * wza;
    wv[4] = wxa * wya * wz;
    wv[5] = wx  * wya * wz;
    wv[6] = wxa * wy  * wz;
    wv[7] = wx  * wy  * wz;

    float a10 = 0.f, a11 = 0.f, a20 = 0.f, a21 = 0.f;
    float b10 = 0.f, b11 = 0.f, b20 = 0.f, b21 = 0.f;
    float st0 = 0.f, st1 = 0.f;

    const size_t lbase = (size_t)l * TSZ;

    if constexpr (PACKED) {
      // one 24B entry per corner: all 5 tables in one cache line
      uint2 e0[8], e1[8], e2[8];
      #pragma unroll
      for (int c = 0; c < 8; ++c) {
        const uint2* p = pk + (lbase + idx[c]) * 3;
        e0[c] = p[0];
        e1[c] = p[1];
        e2[c] = p[2];
      }
      #pragma unroll
      for (int c = 0; c < 8; ++c) {
        const float w = wv[c];
        a10 += bflo(e0[c].x) * w; a11 += bfhi(e0[c].x) * w;
        a20 += bflo(e0[c].y) * w; a21 += bfhi(e0[c].y) * w;
        b10 += bflo(e1[c].x) * w; b11 += bfhi(e1[c].x) * w;
        b20 += bflo(e1[c].y) * w; b21 += bfhi(e1[c].y) * w;
        st0 += bflo(e2[c].x) * w; st1 += bfhi(e2[c].x) * w;
      }
    } else {
      const float2* ba1 = tba1 + lbase;
      const float2* ba2 = tba2 + lbase;
      const float2* bb1 = tbb1 + lbase;
      const float2* bb2 = tbb2 + lbase;
      const float2* bst = tbst + lbase;
      float2 va1[8], va2[8], vb1[8], vb2[8], vst[8];
      #pragma unroll
      for (int c = 0; c < 8; ++c) {
        const unsigned id = idx[c];
        va1[c] = ba1[id];
        va2[c] = ba2[id];
        vb1[c] = bb1[id];
        vb2[c] = bb2[id];
        vst[c] = bst[id];
      }
      #pragma unroll
      for (int c = 0; c < 8; ++c) {
        const float w = wv[c];
        a10 += va1[c].x * w; a11 += va1[c].y * w;
        a20 += va2[c].x * w; a21 += va2[c].y * w;
        b10 += vb1[c].x * w; b11 += vb1[c].y * w;
        b20 += vb2[c].x * w; b21 += vb2[c].y * w;
        st0 += vst[c].x * w; st1 += vst[c].y * w;
      }
    }

    const float ba0f = a10 * prev1 + a20 * next1;
    const float ba1f = a11 * prev1 + a21 * next1;
    const float bb0f = b10 * prev2 + b20 * next2;
    const float bb1f = b11 * prev2 + b21 * next2;

    const float* wr0 = w1 + (size_t)(2 * l) * 64;
    const float* wr1 = w1 + (size_t)(2 * l + 1) * 64;
    const float* wr2 = w1 + (size_t)(32 + 2 * l) * 64;
    const float* wr3 = w1 + (size_t)(33 + 2 * l) * 64;
    const float* wr4 = w1 + (size_t)(64 + 2 * l) * 64;
    const float* wr5 = w1 + (size_t)(65 + 2 * l) * 64;
    #pragma unroll
    for (int j = 0; j < 64; ++j) {
      float acc = h1[j];
      acc += ba0f * wr0[j];
      acc += ba1f * wr1[j];
      acc += bb0f * wr2[j];
      acc += bb1f * wr3[j];
      acc += st0  * wr4[j];
      acc += st1  * wr5[j];
      h1[j] = acc;
    }

    if (l >= 12) {
      const size_t fo = (size_t)(l - 12) * 2;
      float2* o;
      o = reinterpret_cast<float2*>(out + f1base + fo);     *o = make_float2(a10, a11);
      o = reinterpret_cast<float2*>(out + f1base + 8 + fo); *o = make_float2(b10, b11);
      o = reinterpret_cast<float2*>(out + f2base + fo);     *o = make_float2(a20, a21);
      o = reinterpret_cast<float2*>(out + f2base + 8 + fo); *o = make_float2(b20, b21);
    }
  }

  // ---- layer 2: h2 = relu(h1) @ w2 ----
  float h2[16];
  #pragma unroll
  for (int j = 0; j < 16; ++j) h2[j] = 0.0f;
  #pragma unroll
  for (int k = 0; k < 64; ++k) {
    const float a = fmaxf(h1[k], 0.0f);
    #pragma unroll
    for (int j = 0; j < 16; ++j) h2[j] += a * w2[k * 16 + j];
  }

  out[(size_t)3 * NPTS + n] = expf(h2[0]);

  // ---- SH degree 4 ----
  const float dx = dirs[(size_t)n * 3 + 0] * 2.0f - 1.0f;
  const float dy = dirs[(size_t)n * 3 + 1] * 2.0f - 1.0f;
  const float dz = dirs[(size_t)n * 3 + 2] * 2.0f - 1.0f;
  const float xy = dx * dy, xz = dx * dz, yz = dy * dz;
  const float x2 = dx * dx, y2 = dy * dy, z2 = dz * dz;
  float sh[16];
  sh[0]  = 0.28209479177387814f;
  sh[1]  = -0.48860251190291987f * dy;
  sh[2]  = 0.48860251190291987f * dz;
  sh[3]  = -0.48860251190291987f * dx;
  sh[4]  = 1.0925484305920792f * xy;
  sh[5]  = -1.0925484305920792f * yz;
  sh[6]  = 0.94617469575756f * z2 - 0.31539156525252005f;
  sh[7]  = -1.0925484305920792f * xz;
  sh[8]  = 0.5462742152960396f * (x2 - y2);
  sh[9]  = 0.5900435899266435f * dy * (-3.0f * x2 + y2);
  sh[10] = 2.890611442640554f * xy * dz;
  sh[11] = 0.4570457994644657f * dy * (1.0f - 5.0f * z2);
  sh[12] = 0.3731763325901154f * dz * (5.0f * z2 - 3.0f);
  sh[13] = 0.4570457994644657f * dx * (1.0f - 5.0f * z2);
  sh[14] = 1.445305721320277f * dz * (x2 - y2);
  sh[15] = 0.5900435899266435f * dx * (-x2 + 3.0f * y2);

  // ---- c1 ----
  float r1[64];
  #pragma unroll
  for (int j = 0; j < 64; ++j) r1[j] = 0.0f;
  #pragma unroll
  for (int k = 0; k < 16; ++k) {
    const float a = sh[k];
    #pragma unroll
    for (int j = 0; j < 64; ++j) r1[j] += a * wc1[(size_t)k * 64 + j];
  }
  #pragma unroll
  for (int k = 0; k < 16; ++k) {
    const float a = h2[k];
    #pragma unroll
    for (int j = 0; j < 64; ++j) r1[j] += a * wc1[(size_t)(16 + k) * 64 + j];
  }
  #pragma unroll
  for (int j = 0; j < 64; ++j) r1[j] = fmaxf(r1[j], 0.0f);

  // ---- c2 ----
  float r2[64];
  #pragma unroll
  for (int j = 0; j < 64; ++j) r2[j] = 0.0f;
  #pragma unroll
  for (int k = 0; k < 64; ++k) {
    const float a = r1[k];
    #pragma unroll
    for (int j = 0; j < 64; ++j) r2[j] += a * wc2[(size_t)k * 64 + j];
  }

  // ---- c3 + sigmoid ----
  float c0a = 0.f, c1a = 0.f, c2a = 0.f;
  #pragma unroll
  for (int k = 0; k < 64; ++k) {
    const float a = fmaxf(r2[k], 0.0f);
    c0a += a * wc3[k * 3 + 0];
    c1a += a * wc3[k * 3 + 1];
    c2a += a * wc3[k * 3 + 2];
  }
  out[(size_t)n * 3 + 0] = 1.0f / (1.0f + expf(-c0a));
  out[(size_t)n * 3 + 1] = 1.0f / (1.0f + expf(-c1a));
  out[(size_t)n * 3 + 2] = 1.0f / (1.0f + expf(-c2a));
}

extern "C" void kernel_launch(void* const* d_in, const int* in_sizes, int n_in,
                              void* d_out, int out_size, void* d_ws, size_t ws_size,
                              hipStream_t stream) {
  const float* xyzs = (const float*)d_in[0];
  const float* dirs = (const float*)d_in[1];
  const float* ta1  = (const float*)d_in[2];
  const float* ta2  = (const float*)d_in[3];
  const float* tb1  = (const float*)d_in[4];
  const float* tb2  = (const float*)d_in[5];
  const float* tst  = (const float*)d_in[6];
  const float* w1   = (const float*)d_in[7];
  const float* w2   = (const float*)d_in[8];
  const float* wc1  = (const float*)d_in[9];
  const float* wc2  = (const float*)d_in[10];
  const float* wc3  = (const float*)d_in[11];

  LevelParams lp;
  const double B = exp(log(4096.0 / 16.0) / 15.0);
  for (int l = 0; l < LVLS; ++l) {
    const double s = 16.0 * pow(B, (double)l) - 1.0;
    lp.scale[l] = (float)s;
    const int res = (int)ceil(s) + 1;
    lp.res[l] = res;
    lp.dense[l] = ((long long)res * res * res <= (long long)TSZ) ? 1 : 0;
  }

  if (ws_size >= PACKED_BYTES) {
    uint2* packed = (uint2*)d_ws;
    repack_tables<<<(LVLS * TSZ) / 256, 256, 0, stream>>>(
        (const float2*)ta1, (const float2*)ta2, (const float2*)tb1,
        (const float2*)tb2, (const float2*)tst, packed);
    ngp_fused<true><<<NPTS / 256, 256, 0, stream>>>(
        xyzs, dirs, ta1, ta2, tb1, tb2, tst, packed,
        w1, w2, wc1, wc2, wc3, (float*)d_out, lp);
  } else {
    ngp_fused<false><<<NPTS / 256, 256, 0, stream>>>(
        xyzs, dirs, ta1, ta2, tb1, tb2, tst, nullptr,
        w1, w2, wc1, wc2, wc3, (float*)d_out, lp);
  }
}